// Round 12
// baseline (173.283 us; speedup 1.0000x reference)
//
#include <hip/hip_runtime.h>
#include <cstdint>

// ChessGNN forward, MI355X.
// R10: barrier-diet restructure. TPB=384 (6 waves; 360-thread phases 94% use).
//   - merged softmax+aggregation: thread (head,node) does 19-slot softmax AND
//     16-channel aggregation in registers (no P table, no ph5/6 barrier).
//   - BN partials via wave shfl_xor (hh at lane stride 4) + 3KB LDS.
//   - L1: BN-apply+relu fused into MFMA A-frag global load (no phase 2,
//     no overlay hazard) -> k_gat<1> = 4 barriers; k_gat<0> = 6.
//   LDS 37,440B -> 4 blocks/CU. f16 h + f16 outPre (R8 numerics).

#define BB   2048
#define NN   90
#define CC   64
#define NH   4
#define HD   16
#define TPB  384
#define DOUT 128
#define SXP  72      // sx/sh row pitch (f16)
#define SWP  72      // sWt row pitch (f16)

typedef _Float16 f16;
typedef _Float16 f16x4 __attribute__((ext_vector_type(4)));
typedef _Float16 f16x8 __attribute__((ext_vector_type(8)));
typedef float f32x4 __attribute__((ext_vector_type(4)));
union U16x4 { f16x4 v; f16 e[4]; };
union U16x8 { f16x8 v; f16 e[8]; };

// LDS map (bytes), total 37,440:
//  [0,13824)      sh f16[96][72]   (L0: sx in ph2, h after ph3 overlay; L1: h)
//  [13824,23040)  sWt f16[64][72]
//  [23040,29184)  L0: sXr f32[90][17] (ph1-2) | sRed f32[6][4][32] (3072, ph7)
//  [29184,33280)  sInW f32[16][64] (L0)
//  [33280,33536)  sInb f32[64] (L0)
//  [33536,34976)  sSrc f32[360]
//  [34976,36416)  sDst f32[360]
//  [36416,36672)  sAs f32[64]
//  [36672,36928)  sAd f32[64]
//  [36928,37440)  sST f32[128] (L1)
#define LDS_BYTES 37440

template <int LAYER>
__global__ __launch_bounds__(TPB, 4) void k_gat(
    const float* __restrict__ bp,
    const float* __restrict__ inW,
    const float* __restrict__ inb,
    const f16*   __restrict__ prevPre,
    const float* __restrict__ stPrev,
    const float* __restrict__ Wl,
    const float* __restrict__ asrc,
    const float* __restrict__ adst,
    f16*   __restrict__ outPre,
    float* __restrict__ partial,
    float* __restrict__ partialSq)
{
    __shared__ __align__(16) unsigned char lds[LDS_BYTES];
    f16*   sh   = (f16*)lds;                    // [96][72]
    f16*   sWt  = (f16*)(lds + 13824);          // [64][72]
    float* sXr  = (float*)(lds + 23040);        // [90][17] (L0)
    float* sRed = (float*)(lds + 23040);        // [6][4][32] (ph7 overlay)
    float* sInW = (float*)(lds + 29184);        // [16][64] (L0)
    float* sInb = (float*)(lds + 33280);        // [64] (L0)
    float* sSrc = (float*)(lds + 33536);        // [360]
    float* sDst = (float*)(lds + 34976);        // [360]
    float* sAs  = (float*)(lds + 36416);
    float* sAd  = (float*)(lds + 36672);
    float* sST  = (float*)(lds + 36928);        // [128] (L1)

    const int b = blockIdx.x, t = threadIdx.x;
    const int lane = t & 63, wv = t >> 6;
    const int lr = lane & 15, lg = lane >> 4;

    // ---------------- ph1: staging
    for (int i = t; i < CC * CC; i += TPB) {
        int k = i >> 6, c = i & 63;
        sWt[c * SWP + k] = (f16)Wl[i];
    }
    if (t < NH * HD) { sAs[t] = asrc[t]; sAd[t] = adst[t]; }
    if (LAYER == 0) {
        if (t < 108) {   // zero-pad sx rows 90..95 (6 rows x 18 quads)
            int r = t / 18, q = t - r * 18;
            f16x4 z = {(f16)0, (f16)0, (f16)0, (f16)0};
            *(f16x4*)&sh[(NN + r) * SXP + q * 4] = z;
        }
        const float* bpb = bp + (size_t)b * (14 * NN);
        for (int i = t; i < 14 * NN; i += TPB) {
            int p = i / NN, n = i - p * NN;
            sXr[n * 17 + p] = bpb[i];
        }
        if (t < NN) {
            int y = t / 9, x = t - y * 9;
            sXr[t * 17 + 14] = (float)x / 9.0f;
            sXr[t * 17 + 15] = (float)y / 10.0f;
        }
        for (int i = t; i < 16 * CC; i += TPB) sInW[i] = inW[i];
        if (t < CC) sInb[t] = inb[t];
    } else {
        if (t < 2 * CC) sST[t] = stPrev[t];
    }
    __syncthreads();

    if (LAYER == 0) {
        // ------------ ph2 (L0): x = board @ inW + b -> sh (as sx, f16)
        for (int i = t; i < NN * 16; i += TPB) {
            int n = i >> 4, c4 = (i & 15) << 2;
            float a0 = 0, a1 = 0, a2 = 0, a3 = 0;
            #pragma unroll
            for (int k = 0; k < 16; k++) {
                float4 w = *(const float4*)&sInW[k * CC + c4];
                float xv = sXr[n * 17 + k];
                a0 = fmaf(xv, w.x, a0); a1 = fmaf(xv, w.y, a1);
                a2 = fmaf(xv, w.z, a2); a3 = fmaf(xv, w.w, a3);
            }
            float4 bias = *(const float4*)&sInb[c4];
            f16x4 o;
            o.x = (f16)(a0 + bias.x); o.y = (f16)(a1 + bias.y);
            o.z = (f16)(a2 + bias.z); o.w = (f16)(a3 + bias.w);
            *(f16x4*)&sh[n * SXP + c4] = o;
        }
        __syncthreads();

        // ------------ ph3 (L0): h = x @ W via MFMA (frag preload + overlay)
        {
            const int mt = wv;   // 6 waves x 1 M-tile, 4 N-tiles each
            const f16x8 af0 = *(const f16x8*)&sh[(mt * 16 + lr) * SXP + lg * 8];
            const f16x8 af1 = *(const f16x8*)&sh[(mt * 16 + lr) * SXP + 32 + lg * 8];
            f16x8 bf0[4], bf1[4];
            #pragma unroll
            for (int nt = 0; nt < 4; nt++) {
                bf0[nt] = *(const f16x8*)&sWt[(nt * 16 + lr) * SWP + lg * 8];
                bf1[nt] = *(const f16x8*)&sWt[(nt * 16 + lr) * SWP + 32 + lg * 8];
            }
            __syncthreads();   // all sx reads done; h overlay writes may begin
            #pragma unroll
            for (int nt = 0; nt < 4; nt++) {
                f32x4 acc = {0.0f, 0.0f, 0.0f, 0.0f};
                acc = __builtin_amdgcn_mfma_f32_16x16x32_f16(af0, bf0[nt], acc, 0, 0, 0);
                acc = __builtin_amdgcn_mfma_f32_16x16x32_f16(af1, bf1[nt], acc, 0, 0, 0);
                const int row = mt * 16 + lg * 4, col = nt * 16 + lr;
                sh[(row + 0) * SXP + col] = (f16)acc[0];
                sh[(row + 1) * SXP + col] = (f16)acc[1];
                sh[(row + 2) * SXP + col] = (f16)acc[2];
                sh[(row + 3) * SXP + col] = (f16)acc[3];
            }
        }
        __syncthreads();
    } else {
        // ------------ ph3 (L1): A-frags from global w/ fused BN+relu; no ph2
        {
            const int mt = wv;
            const int row = mt * 16 + lr;
            U16x8 va, vb;
            va.v = (f16x8){};  vb.v = (f16x8){};
            if (row < NN) {
                const f16* pp = prevPre + ((size_t)b * NN + row) * CC;
                va.v = *(const f16x8*)&pp[lg * 8];
                vb.v = *(const f16x8*)&pp[32 + lg * 8];
            }
            U16x8 a0u, a1u;
            #pragma unroll
            for (int j = 0; j < 8; j++) {
                float v0 = fmaf((float)va.e[j], sST[lg * 8 + j],      sST[64 + lg * 8 + j]);
                float v1 = fmaf((float)vb.e[j], sST[32 + lg * 8 + j], sST[96 + lg * 8 + j]);
                a0u.e[j] = (f16)(v0 > 0.0f ? v0 : 0.0f);
                a1u.e[j] = (f16)(v1 > 0.0f ? v1 : 0.0f);
            }
            #pragma unroll
            for (int nt = 0; nt < 4; nt++) {
                f16x8 bf0 = *(const f16x8*)&sWt[(nt * 16 + lr) * SWP + lg * 8];
                f16x8 bf1 = *(const f16x8*)&sWt[(nt * 16 + lr) * SWP + 32 + lg * 8];
                f32x4 acc = {0.0f, 0.0f, 0.0f, 0.0f};
                acc = __builtin_amdgcn_mfma_f32_16x16x32_f16(a0u.v, bf0, acc, 0, 0, 0);
                acc = __builtin_amdgcn_mfma_f32_16x16x32_f16(a1u.v, bf1, acc, 0, 0, 0);
                const int orow = mt * 16 + lg * 4, col = nt * 16 + lr;
                sh[(orow + 0) * SXP + col] = (f16)acc[0];
                sh[(orow + 1) * SXP + col] = (f16)acc[1];
                sh[(orow + 2) * SXP + col] = (f16)acc[2];
                sh[(orow + 3) * SXP + col] = (f16)acc[3];
            }
        }
        __syncthreads();
    }

    // ---------------- ph4: attention scores (t<360; hh=t&3, n=t>>2)
    if (t < NH * NN) {
        int hh = t & 3, n = t >> 2;
        U16x8 h0, h1;
        h0.v = *(const f16x8*)&sh[n * SXP + hh * HD];
        h1.v = *(const f16x8*)&sh[n * SXP + hh * HD + 8];
        float a = 0.0f, d = 0.0f;
        #pragma unroll
        for (int j = 0; j < 8; j++) {
            a = fmaf((float)h0.e[j], sAs[hh * HD + j], a);
            a = fmaf((float)h1.e[j], sAs[hh * HD + 8 + j], a);
            d = fmaf((float)h0.e[j], sAd[hh * HD + j], d);
            d = fmaf((float)h1.e[j], sAd[hh * HD + 8 + j], d);
        }
        sSrc[hh * NN + n] = a;
        sDst[hh * NN + n] = d;
    }
    __syncthreads();

    // ---------------- ph5+6 merged: softmax + 16-ch aggregation in regs
    float sum[16], sq[16];
    #pragma unroll
    for (int q = 0; q < 16; q++) { sum[q] = 0.0f; sq[q] = 0.0f; }
    if (t < NH * NN) {
        const int hh = t & 3, n = t >> 2;
        const int y = n / 9, x = n - y * 9;
        const float si = sSrc[hh * NN + n];
        const float* dst = &sDst[hh * NN];
        float e[19];
        #pragma unroll
        for (int xx = 0; xx < 9; xx++) {
            int dx = xx > x ? xx - x : x - xx;
            float ee = si + dst[y * 9 + xx];
            ee = ee > 0.0f ? ee : 0.2f * ee;
            e[xx] = (dx <= 4) ? ee : -1e30f;
        }
        #pragma unroll
        for (int yy = 0; yy < 10; yy++) {
            int dy = yy > y ? yy - y : y - yy;
            float ee = si + dst[yy * 9 + x];
            ee = ee > 0.0f ? ee : 0.2f * ee;
            e[9 + yy] = (dy >= 1 && dy <= 5) ? ee : -1e30f;
        }
        float m = e[0];
        #pragma unroll
        for (int k = 1; k < 19; k++) m = fmaxf(m, e[k]);
        float acc[16];
        #pragma unroll
        for (int q = 0; q < 16; q++) acc[q] = 0.0f;
        float s = 0.0f;
        #pragma unroll
        for (int k = 0; k < 19; k++) {
            float p = __expf(e[k] - m);   // invalid slots: exp(-huge) = 0
            s += p;
            int j = (k < 9) ? (y * 9 + k) : ((k - 9) * 9 + x);
            U16x8 h0, h1;
            h0.v = *(const f16x8*)&sh[j * SXP + hh * HD];
            h1.v = *(const f16x8*)&sh[j * SXP + hh * HD + 8];
            #pragma unroll
            for (int q = 0; q < 8; q++) {
                acc[q]     = fmaf((float)h0.e[q], p, acc[q]);
                acc[8 + q] = fmaf((float)h1.e[q], p, acc[8 + q]);
            }
        }
        float inv = 1.0f / s;
        U16x8 o0, o1;
        #pragma unroll
        for (int q = 0; q < 8; q++) {
            o0.e[q] = (f16)(acc[q] * inv);
            o1.e[q] = (f16)(acc[8 + q] * inv);
        }
        f16* op = outPre + ((size_t)b * NN + n) * CC + hh * HD;
        *(f16x8*)op = o0.v;
        *(f16x8*)(op + 8) = o1.v;
        #pragma unroll
        for (int q = 0; q < 8; q++) {   // BN stats from the CAST values
            float r0 = (float)o0.e[q], r1 = (float)o1.e[q];
            sum[q] = r0;     sq[q] = r0 * r0;
            sum[8 + q] = r1; sq[8 + q] = r1 * r1;
        }
    }
    // wave shfl reduce over same-hh lanes (stride 4) — ALL threads participate
    #pragma unroll
    for (int q = 0; q < 16; q++) {
        float v = sum[q];
        v += __shfl_xor(v, 4); v += __shfl_xor(v, 8);
        v += __shfl_xor(v, 16); v += __shfl_xor(v, 32);
        sum[q] = v;
        float w2 = sq[q];
        w2 += __shfl_xor(w2, 4); w2 += __shfl_xor(w2, 8);
        w2 += __shfl_xor(w2, 16); w2 += __shfl_xor(w2, 32);
        sq[q] = w2;
    }
    if (lane < 4) {   // lane == hh of this lane's reduced group
        float* dstp = &sRed[(wv * 4 + lane) * 32];
        #pragma unroll
        for (int q4 = 0; q4 < 4; q4++) {
            float4 a, c;
            a.x = sum[q4 * 4 + 0]; a.y = sum[q4 * 4 + 1];
            a.z = sum[q4 * 4 + 2]; a.w = sum[q4 * 4 + 3];
            c.x = sq[q4 * 4 + 0];  c.y = sq[q4 * 4 + 1];
            c.z = sq[q4 * 4 + 2];  c.w = sq[q4 * 4 + 3];
            *(float4*)&dstp[q4 * 4] = a;
            *(float4*)&dstp[16 + q4 * 4] = c;
        }
    }
    __syncthreads();

    // ---------------- ph7: final per-channel partials
    if (t < CC) {
        int hh = t >> 4, q = t & 15;
        float s = 0.0f, ss = 0.0f;
        #pragma unroll
        for (int w = 0; w < 6; w++) {
            s  += sRed[(w * 4 + hh) * 32 + q];
            ss += sRed[(w * 4 + hh) * 32 + 16 + q];
        }
        partial[(size_t)b * CC + t] = s;
        partialSq[(size_t)b * CC + t] = ss;
    }
}

// ------------------------------------------------------------- BN statistics
__global__ __launch_bounds__(256) void k_stats(
    const float* __restrict__ partial, const float* __restrict__ partialSq,
    const float* __restrict__ gamma, const float* __restrict__ beta,
    float* __restrict__ st)
{
    const int c = blockIdx.x, t = threadIdx.x;
    float s = 0.0f, q = 0.0f;
    for (int b = t; b < BB; b += 256) {
        s += partial[(size_t)b * CC + c];
        q += partialSq[(size_t)b * CC + c];
    }
    __shared__ float rs[256], rq[256];
    rs[t] = s; rq[t] = q;
    __syncthreads();
    for (int o = 128; o > 0; o >>= 1) {
        if (t < o) { rs[t] += rs[t + o]; rq[t] += rq[t + o]; }
        __syncthreads();
    }
    if (t == 0) {
        const float cntInv = 1.0f / (float)(BB * NN);
        float mean = rs[0] * cntInv;
        float var  = rq[0] * cntInv - mean * mean;
        float sc = gamma[c] * rsqrtf(var + 1e-5f);
        st[c] = sc;
        st[CC + c] = beta[c] - mean * sc;
    }
}

// ------------------------------------------------------------------- final
__global__ __launch_bounds__(256) void k_final(
    const f16* __restrict__ pre, const float* __restrict__ st,
    const float* __restrict__ outW, const float* __restrict__ outb,
    float* __restrict__ out)
{
    __shared__ float sM[CC];
    __shared__ float sPart[4][CC];
    const int b = blockIdx.x, t = threadIdx.x;
    const int c = t & 63, p = t >> 6;
    const f16* pv = pre + (size_t)b * (NN * CC);
    float s = st[c], sft = st[CC + c];
    float a = 0.0f;
    int nBeg = p * 23, nEnd = nBeg + 23 < NN ? nBeg + 23 : NN;
    for (int n = nBeg; n < nEnd; n++) {
        float v = fmaf((float)pv[n * CC + c], s, sft);
        a += (v > 0.0f ? v : 0.0f);
    }
    sPart[p][c] = a;
    __syncthreads();
    if (t < CC)
        sM[t] = (sPart[0][t] + sPart[1][t] + sPart[2][t] + sPart[3][t]) * (1.0f / (float)NN);
    __syncthreads();
    if (t < DOUT) {
        float acc = outb[t];
        #pragma unroll
        for (int cc2 = 0; cc2 < CC; cc2++) acc = fmaf(sM[cc2], outW[cc2 * DOUT + t], acc);
        out[(size_t)b * DOUT + t] = acc;
    }
}

// ------------------------------------------------------------------ launch
extern "C" void kernel_launch(void* const* d_in, const int* in_sizes, int n_in,
                              void* d_out, int out_size, void* d_ws, size_t ws_size,
                              hipStream_t stream) {
    (void)in_sizes; (void)n_in; (void)out_size; (void)ws_size;

    const float* bp   = (const float*)d_in[0];
    const float* inW  = (const float*)d_in[1];
    const float* inb  = (const float*)d_in[2];
    const float* W0   = (const float*)d_in[3];
    const float* as0  = (const float*)d_in[4];
    const float* ad0  = (const float*)d_in[5];
    const float* g0   = (const float*)d_in[6];
    const float* b0   = (const float*)d_in[7];
    const float* W1   = (const float*)d_in[8];
    const float* as1  = (const float*)d_in[9];
    const float* ad1  = (const float*)d_in[10];
    const float* g1   = (const float*)d_in[11];
    const float* b1   = (const float*)d_in[12];
    const float* outW = (const float*)d_in[13];
    const float* outb = (const float*)d_in[14];
    float* out = (float*)d_out;

    unsigned char* ws = (unsigned char*)d_ws;
    f16*   outPre    = (f16*)ws;                           // 23,592,960 B
    float* partial   = (float*)(ws + 23592960);            // 524,288 B
    float* partialSq = (float*)(ws + 23592960 + 524288);   // 524,288 B
    float* st0       = (float*)(ws + 23592960 + 1048576);
    float* st1       = st0 + 2 * CC;

    k_gat<0><<<BB, TPB, 0, stream>>>(bp, inW, inb, nullptr, nullptr,
                                     W0, as0, ad0, outPre, partial, partialSq);
    k_stats<<<CC, 256, 0, stream>>>(partial, partialSq, g0, b0, st0);
    k_gat<1><<<BB, TPB, 0, stream>>>(nullptr, nullptr, nullptr, outPre, st0,
                                     W1, as1, ad1, outPre, partial, partialSq);
    k_stats<<<CC, 256, 0, stream>>>(partial, partialSq, g1, b1, st1);
    k_final<<<BB, 256, 0, stream>>>(outPre, st1, outW, outb, out);
}

// Round 13
// 122.941 us; speedup vs baseline: 1.4095x; 1.4095x over previous
//
#include <hip/hip_runtime.h>
#include <cstdint>

// ChessGNN forward, MI355X.
// R11 = R8 base + (a) phase-6 8-channel mapping (b128 h reads, LDS instrs
//       halved; shfl BN reduce) + (b) phase-4 scores via MFMA (block-diagonal
//       [as|ad] B table). Live register state kept < 35 floats (spill rule).

#define BB   2048
#define NN   90
#define NP   96
#define CC   64
#define NH   4
#define HD   16
#define TPB  512
#define DOUT 128
#define SXP  72      // sx / sh16 row pitch (f16)
#define SWP  72      // sWt row pitch (f16)
#define PPITCH 20    // sPh row pitch (f16)
#define NSLOT 19

typedef _Float16 f16;
typedef _Float16 f16x4 __attribute__((ext_vector_type(4)));
typedef _Float16 f16x8 __attribute__((ext_vector_type(8)));
typedef float f32x4 __attribute__((ext_vector_type(4)));
union U16x4 { f16x4 v; f16 e[4]; };
union U16x8 { f16x8 v; f16 e[8]; };

// LDS (38,976 B total):
//  big[13824]: sx f16[96][72] -> sh16 f16[96][72] (phase-3 overlay)
//  uni[19712]: ph1-3: sWt f16[64][72] [0,9216) | sInW f32[16][64] [9216,13312)
//              | sInb f32[64] [13312,13568) | sXr f32[90][17] [13568,19688)
//              ph5-6: sPh f16[360][20] [0,14400)
//              ph7:   sRa f32[8][64] [0,2048) | sRb f32[8][64] [8192,10240)
//  sSrc/sDst f32[4][90] | sAB f16[16][64] | sST f32[128]

template <int LAYER>
__global__ __launch_bounds__(TPB, 6) void k_gat(
    const float* __restrict__ bp,
    const float* __restrict__ inW,
    const float* __restrict__ inb,
    const f16*   __restrict__ prevPre,
    const float* __restrict__ stPrev,
    const float* __restrict__ Wl,
    const float* __restrict__ asrc,
    const float* __restrict__ adst,
    f16*   __restrict__ outPre,
    float* __restrict__ partial,
    float* __restrict__ partialSq)
{
    __shared__ __align__(16) unsigned char big[13824];
    __shared__ __align__(16) unsigned char uni[19712];
    __shared__ float sSrc[NH][NN], sDst[NH][NN];
    __shared__ __align__(16) f16 sAB[16 * CC];
    __shared__ float sST[2 * CC];

    f16*   sx   = (f16*)big;                // [96][72] phases 1-3
    f16*   sh16 = (f16*)big;                // [96][72] phases 3-6 (overlay)
    f16*   sWt  = (f16*)uni;
    float* sInW = (float*)(uni + 9216);
    float* sInb = (float*)(uni + 13312);
    float* sXr  = (float*)(uni + 13568);
    f16*   sPh  = (f16*)uni;
    float* sRa  = (float*)uni;
    float* sRb  = (float*)(uni + 8192);

    const int b = blockIdx.x, t = threadIdx.x;
    const int cq = t & 15, ng = t >> 4;
    const int c4 = cq << 2;
    const int jcnt = (ng < NN - 64) ? 3 : 2;
    const int lane = t & 63, wv = t >> 6;
    const int lr = lane & 15, lg = lane >> 4;

    // ---------------- phase 1: stage weights / inputs; zero-pad sx rows 90-95
    for (int i = t; i < CC * CC; i += TPB) {
        int k = i >> 6, c = i & 63;
        sWt[c * SWP + k] = (f16)Wl[i];
    }
    // block-diagonal score table: sAB[c][k] (c<4: asrc head c; c 4-7: adst)
    for (int i = t; i < 16 * CC; i += TPB) {
        int c = i >> 6, k = i & 63;
        float v = 0.0f;
        if (c < 4)      { if ((k >> 4) == c)     v = asrc[k]; }
        else if (c < 8) { if ((k >> 4) == c - 4) v = adst[k]; }
        sAB[i] = (f16)v;
    }
    if (t < (NP - NN) * (SXP / 4)) {
        int r = t / (SXP / 4), q = t - r * (SXP / 4);
        f16x4 z = {(f16)0, (f16)0, (f16)0, (f16)0};
        *(f16x4*)&sx[(NN + r) * SXP + q * 4] = z;
    }
    if (LAYER == 0) {
        for (int i = t; i < 16 * CC; i += TPB) sInW[i] = inW[i];
        if (t < CC) sInb[t] = inb[t];
        const float* bpb = bp + (size_t)b * (14 * NN);
        for (int i = t; i < 14 * NN; i += TPB) {
            int p = i / NN, n = i - p * NN;
            sXr[n * 17 + p] = bpb[i];
        }
        if (t < NN) {
            int y = t / 9, x = t - y * 9;
            sXr[t * 17 + 14] = (float)x / 9.0f;
            sXr[t * 17 + 15] = (float)y / 10.0f;
        }
    } else {
        if (t < 2 * CC) sST[t] = stPrev[t];
    }
    __syncthreads();

    // ---------------- phase 2: x -> sx (f16)
    if (LAYER == 0) {
        const int n0 = ng, n1 = ng + 32, n2 = (jcnt == 3) ? ng + 64 : ng;
        float acc[3][4] = {};
        #pragma unroll 4
        for (int k = 0; k < 16; k++) {
            float4 w = *(const float4*)&sInW[k * CC + c4];
            float x0 = sXr[n0 * 17 + k], x1 = sXr[n1 * 17 + k], x2 = sXr[n2 * 17 + k];
            acc[0][0] = fmaf(x0, w.x, acc[0][0]); acc[0][1] = fmaf(x0, w.y, acc[0][1]);
            acc[0][2] = fmaf(x0, w.z, acc[0][2]); acc[0][3] = fmaf(x0, w.w, acc[0][3]);
            acc[1][0] = fmaf(x1, w.x, acc[1][0]); acc[1][1] = fmaf(x1, w.y, acc[1][1]);
            acc[1][2] = fmaf(x1, w.z, acc[1][2]); acc[1][3] = fmaf(x1, w.w, acc[1][3]);
            acc[2][0] = fmaf(x2, w.x, acc[2][0]); acc[2][1] = fmaf(x2, w.y, acc[2][1]);
            acc[2][2] = fmaf(x2, w.z, acc[2][2]); acc[2][3] = fmaf(x2, w.w, acc[2][3]);
        }
        float4 bias = *(const float4*)&sInb[c4];
        for (int j = 0; j < jcnt; j++) {
            int n = ng + 32 * j;
            f16x4 o;
            o.x = (f16)(acc[j][0] + bias.x);
            o.y = (f16)(acc[j][1] + bias.y);
            o.z = (f16)(acc[j][2] + bias.z);
            o.w = (f16)(acc[j][3] + bias.w);
            *(f16x4*)&sx[n * SXP + c4] = o;
        }
    } else {
        const f16x8* pv8 = (const f16x8*)(prevPre + (size_t)b * (NN * CC));
        for (int i8 = t; i8 < NN * CC / 8; i8 += TPB) {
            U16x8 v; v.v = pv8[i8];
            int n = i8 >> 3, c8 = (i8 & 7) << 3;
            U16x8 o;
            #pragma unroll
            for (int j = 0; j < 8; j++) {
                float a = fmaf((float)v.e[j], sST[c8 + j], sST[CC + c8 + j]);
                o.e[j] = (f16)(a > 0.0f ? a : 0.0f);
            }
            *(f16x8*)&sx[n * SXP + c8] = o.v;
        }
    }
    __syncthreads();

    // ---------------- phase 3: h = x @ W via MFMA; C cast f16 over sx
    {
        const int nt = wv & 3, m0 = wv >> 2;
        const f16x8 bf0 = *(const f16x8*)&sWt[(nt * 16 + lr) * SWP + lg * 8];
        const f16x8 bf1 = *(const f16x8*)&sWt[(nt * 16 + lr) * SWP + 32 + lg * 8];
        f16x8 af0[3], af1[3];
        #pragma unroll
        for (int mi = 0; mi < 3; mi++) {
            const int mt = m0 + 2 * mi;
            af0[mi] = *(const f16x8*)&sx[(mt * 16 + lr) * SXP + lg * 8];
            af1[mi] = *(const f16x8*)&sx[(mt * 16 + lr) * SXP + 32 + lg * 8];
        }
        __syncthreads();   // all sx/sWt reads done; sh16 writes may begin
        #pragma unroll
        for (int mi = 0; mi < 3; mi++) {
            const int mt = m0 + 2 * mi;
            f32x4 acc = {0.0f, 0.0f, 0.0f, 0.0f};
            acc = __builtin_amdgcn_mfma_f32_16x16x32_f16(af0[mi], bf0, acc, 0, 0, 0);
            acc = __builtin_amdgcn_mfma_f32_16x16x32_f16(af1[mi], bf1, acc, 0, 0, 0);
            const int row = mt * 16 + lg * 4, col = nt * 16 + lr;
            #pragma unroll
            for (int r = 0; r < 4; r++)
                sh16[(row + r) * SXP + col] = (f16)acc[r];
        }
    }
    __syncthreads();

    // ---------------- phase 4: scores via MFMA (h @ [as|ad]^T blockdiag)
    {
        const int mt = wv;            // 6 M-tiles; waves 6,7 idle
        if (mt < 6) {
            f16x8 a0 = *(const f16x8*)&sh16[(mt * 16 + lr) * SXP + lg * 8];
            f16x8 a1 = *(const f16x8*)&sh16[(mt * 16 + lr) * SXP + 32 + lg * 8];
            f16x8 b0 = *(const f16x8*)&sAB[lr * CC + lg * 8];
            f16x8 b1 = *(const f16x8*)&sAB[lr * CC + 32 + lg * 8];
            f32x4 acc = {0.0f, 0.0f, 0.0f, 0.0f};
            acc = __builtin_amdgcn_mfma_f32_16x16x32_f16(a0, b0, acc, 0, 0, 0);
            acc = __builtin_amdgcn_mfma_f32_16x16x32_f16(a1, b1, acc, 0, 0, 0);
            const int row = mt * 16 + lg * 4;
            if (lr < 8) {
                float* dstbuf = (lr < 4) ? &sSrc[lr][0] : &sDst[lr - 4][0];
                #pragma unroll
                for (int r = 0; r < 4; r++)
                    if (row + r < NN) dstbuf[row + r] = acc[r];
            }
        }
    }
    __syncthreads();

    // ---------------- phase 5: positional-slot softmax -> sPh (f16, normalized)
    if (t < NH * NN) {
        int hh = t / NN, n = t - hh * NN;
        int y = n / 9, x = n - y * 9;
        float si = sSrc[hh][n];
        float e[NSLOT];
        #pragma unroll
        for (int xx = 0; xx < 9; xx++) {
            int dx = xx > x ? xx - x : x - xx;
            float ee = si + sDst[hh][y * 9 + xx];
            ee = ee > 0.0f ? ee : 0.2f * ee;
            e[xx] = (dx <= 4) ? ee : -1e30f;
        }
        #pragma unroll
        for (int yy = 0; yy < 10; yy++) {
            int dy = yy > y ? yy - y : y - yy;
            float ee = si + sDst[hh][yy * 9 + x];
            ee = ee > 0.0f ? ee : 0.2f * ee;
            e[9 + yy] = (dy >= 1 && dy <= 5) ? ee : -1e30f;
        }
        float m = e[0];
        #pragma unroll
        for (int k = 1; k < NSLOT; k++) m = fmaxf(m, e[k]);
        float p[NSLOT];
        float s = 0.0f;
        #pragma unroll
        for (int k = 0; k < NSLOT; k++) { p[k] = __expf(e[k] - m); s += p[k]; }
        float inv = 1.0f / s;
        f16* pr = &sPh[t * PPITCH];
        #pragma unroll
        for (int q = 0; q < 5; q++) {
            U16x4 o;
            #pragma unroll
            for (int j = 0; j < 4; j++) {
                int k = 4 * q + j;
                o.e[j] = (k < NSLOT) ? (f16)(p[k] * inv) : (f16)0;
            }
            *(f16x4*)&pr[4 * q] = o.v;
        }
    }
    __syncthreads();

    // ---------------- phase 6: out = attn @ h, 8 channels/thread (b128 reads)
    const int c8i = t & 7, nr = t >> 3;
    const int ch = c8i << 3, hh6 = c8i >> 1;
    float lsum[8] = {}, lsq[8] = {};
    f16* op = outPre + (size_t)b * (NN * CC);
    #pragma unroll
    for (int j = 0; j < 2; j++) {
        int n = nr + 64 * j;
        if (n < NN) {
            int y = n / 9, x = n - y * 9;
            const f16* pr = &sPh[(hh6 * NN + n) * PPITCH];
            U16x4 P0, P1, P2, P3, P4;
            P0.v = *(const f16x4*)&pr[0];
            P1.v = *(const f16x4*)&pr[4];
            P2.v = *(const f16x4*)&pr[8];
            P3.v = *(const f16x4*)&pr[12];
            P4.v = *(const f16x4*)&pr[16];
            float a[8] = {};
            #pragma unroll
            for (int xx = 0; xx < 9; xx++) {
                float p = (xx < 4) ? (float)P0.e[xx]
                        : (xx < 8) ? (float)P1.e[xx - 4] : (float)P2.e[0];
                U16x8 h8; h8.v = *(const f16x8*)&sh16[(y * 9 + xx) * SXP + ch];
                #pragma unroll
                for (int q = 0; q < 8; q++) a[q] = fmaf((float)h8.e[q], p, a[q]);
            }
            #pragma unroll
            for (int yy = 0; yy < 10; yy++) {
                int k = 9 + yy;
                float p = (k < 12) ? (float)P2.e[k - 8]
                        : (k < 16) ? (float)P3.e[k - 12] : (float)P4.e[k - 16];
                U16x8 h8; h8.v = *(const f16x8*)&sh16[(yy * 9 + x) * SXP + ch];
                #pragma unroll
                for (int q = 0; q < 8; q++) a[q] = fmaf((float)h8.e[q], p, a[q]);
            }
            U16x8 o;
            #pragma unroll
            for (int q = 0; q < 8; q++) o.e[q] = (f16)a[q];
            *(f16x8*)&op[n * CC + ch] = o.v;
            #pragma unroll
            for (int q = 0; q < 8; q++) {
                float r = (float)o.e[q];
                lsum[q] += r;
                lsq[q] = fmaf(r, r, lsq[q]);
            }
        }
    }
    __syncthreads();   // sPh dead beyond here

    // ---------------- phase 7: BN partials (shfl over same-c8i lanes)
    #pragma unroll
    for (int q = 0; q < 8; q++) {
        float v = lsum[q];
        v += __shfl_xor(v, 8); v += __shfl_xor(v, 16); v += __shfl_xor(v, 32);
        lsum[q] = v;
        float w2 = lsq[q];
        w2 += __shfl_xor(w2, 8); w2 += __shfl_xor(w2, 16); w2 += __shfl_xor(w2, 32);
        lsq[q] = w2;
    }
    if (lane < 8) {      // lane == c8i
        float4 a0, a1, c0, c1;
        a0.x = lsum[0]; a0.y = lsum[1]; a0.z = lsum[2]; a0.w = lsum[3];
        a1.x = lsum[4]; a1.y = lsum[5]; a1.z = lsum[6]; a1.w = lsum[7];
        c0.x = lsq[0];  c0.y = lsq[1];  c0.z = lsq[2];  c0.w = lsq[3];
        c1.x = lsq[4];  c1.y = lsq[5];  c1.z = lsq[6];  c1.w = lsq[7];
        *(float4*)&sRa[wv * CC + lane * 8]     = a0;
        *(float4*)&sRa[wv * CC + lane * 8 + 4] = a1;
        *(float4*)&sRb[wv * CC + lane * 8]     = c0;
        *(float4*)&sRb[wv * CC + lane * 8 + 4] = c1;
    }
    __syncthreads();
    if (t < CC) {
        float s = 0.0f, q2 = 0.0f;
        #pragma unroll
        for (int w = 0; w < 8; w++) {
            s  += sRa[w * CC + t];
            q2 += sRb[w * CC + t];
        }
        partial[(size_t)b * CC + t] = s;
        partialSq[(size_t)b * CC + t] = q2;
    }
}

// ------------------------------------------------------------- BN statistics
__global__ __launch_bounds__(256) void k_stats(
    const float* __restrict__ partial, const float* __restrict__ partialSq,
    const float* __restrict__ gamma, const float* __restrict__ beta,
    float* __restrict__ st)
{
    const int c = blockIdx.x, t = threadIdx.x;
    float s = 0.0f, q = 0.0f;
    for (int b = t; b < BB; b += 256) {
        s += partial[(size_t)b * CC + c];
        q += partialSq[(size_t)b * CC + c];
    }
    __shared__ float rs[256], rq[256];
    rs[t] = s; rq[t] = q;
    __syncthreads();
    for (int o = 128; o > 0; o >>= 1) {
        if (t < o) { rs[t] += rs[t + o]; rq[t] += rq[t + o]; }
        __syncthreads();
    }
    if (t == 0) {
        const float cntInv = 1.0f / (float)(BB * NN);
        float mean = rs[0] * cntInv;
        float var  = rq[0] * cntInv - mean * mean;
        float sc = gamma[c] * rsqrtf(var + 1e-5f);
        st[c] = sc;
        st[CC + c] = beta[c] - mean * sc;
    }
}

// ------------------------------------------------------------------- final
__global__ __launch_bounds__(256) void k_final(
    const f16* __restrict__ pre, const float* __restrict__ st,
    const float* __restrict__ outW, const float* __restrict__ outb,
    float* __restrict__ out)
{
    __shared__ float sM[CC];
    __shared__ float sPart[4][CC];
    const int b = blockIdx.x, t = threadIdx.x;
    const int c = t & 63, p = t >> 6;
    const f16* pv = pre + (size_t)b * (NN * CC);
    float s = st[c], sft = st[CC + c];
    float a = 0.0f;
    int nBeg = p * 23, nEnd = nBeg + 23 < NN ? nBeg + 23 : NN;
    for (int n = nBeg; n < nEnd; n++) {
        float v = fmaf((float)pv[n * CC + c], s, sft);
        a += (v > 0.0f ? v : 0.0f);
    }
    sPart[p][c] = a;
    __syncthreads();
    if (t < CC)
        sM[t] = (sPart[0][t] + sPart[1][t] + sPart[2][t] + sPart[3][t]) * (1.0f / (float)NN);
    __syncthreads();
    if (t < DOUT) {
        float acc = outb[t];
        #pragma unroll
        for (int cc2 = 0; cc2 < CC; cc2++) acc = fmaf(sM[cc2], outW[cc2 * DOUT + t], acc);
        out[(size_t)b * DOUT + t] = acc;
    }
}

// ------------------------------------------------------------------ launch
extern "C" void kernel_launch(void* const* d_in, const int* in_sizes, int n_in,
                              void* d_out, int out_size, void* d_ws, size_t ws_size,
                              hipStream_t stream) {
    (void)in_sizes; (void)n_in; (void)out_size; (void)ws_size;

    const float* bp   = (const float*)d_in[0];
    const float* inW  = (const float*)d_in[1];
    const float* inb  = (const float*)d_in[2];
    const float* W0   = (const float*)d_in[3];
    const float* as0  = (const float*)d_in[4];
    const float* ad0  = (const float*)d_in[5];
    const float* g0   = (const float*)d_in[6];
    const float* b0   = (const float*)d_in[7];
    const float* W1   = (const float*)d_in[8];
    const float* as1  = (const float*)d_in[9];
    const float* ad1  = (const float*)d_in[10];
    const float* g1   = (const float*)d_in[11];
    const float* b1   = (const float*)d_in[12];
    const float* outW = (const float*)d_in[13];
    const float* outb = (const float*)d_in[14];
    float* out = (float*)d_out;

    unsigned char* ws = (unsigned char*)d_ws;
    f16*   outPre    = (f16*)ws;                           // 23,592,960 B
    float* partial   = (float*)(ws + 23592960);            // 524,288 B
    float* partialSq = (float*)(ws + 23592960 + 524288);   // 524,288 B
    float* st0       = (float*)(ws + 23592960 + 1048576);
    float* st1       = st0 + 2 * CC;

    k_gat<0><<<BB, TPB, 0, stream>>>(bp, inW, inb, nullptr, nullptr,
                                     W0, as0, ad0, outPre, partial, partialSq);
    k_stats<<<CC, 256, 0, stream>>>(partial, partialSq, g0, b0, st0);
    k_gat<1><<<BB, TPB, 0, stream>>>(nullptr, nullptr, nullptr, outPre, st0,
                                     W1, as1, ad1, outPre, partial, partialSq);
    k_stats<<<CC, 256, 0, stream>>>(partial, partialSq, g1, b1, st1);
    k_final<<<BB, 256, 0, stream>>>(outPre, st1, outW, outb, out);
}

// Round 14
// 110.706 us; speedup vs baseline: 1.5653x; 1.1105x over previous
//
#include <hip/hip_runtime.h>
#include <cstdint>

// ChessGNN forward, MI355X.
// R12 = R4 base (best measured: 109.0us) + ONE proven delta from R8:
//   phase-5 softmax normalizes in REGISTERS and stores P via 5x b64 vector
//   stores (R4 did a scalar in-LDS "*= inv" pass: 38 extra scalar LDS ops
//   per thread -> bank conflicts). Phase 6 drops the trailing inv multiply.
// Everything else byte-identical to R4 (f32 h via MFMA-overlay, f32 outPre).

#define BB   2048
#define NN   90
#define NP   96      // padded node count for MFMA M-tiles
#define CC   64
#define NH   4
#define HD   16
#define TPB  512
#define DOUT 128
#define SWP  72      // sWt row pitch (f16)
#define SHP  72      // shF row pitch (f32) / sx row pitch (f16)
#define PPITCH 24    // sPh row pitch (f16), 48B rows
#define NSLOT 19     // 9 row slots + 10 col slots

typedef _Float16 f16;
typedef _Float16 f16x4 __attribute__((ext_vector_type(4)));
typedef _Float16 f16x8 __attribute__((ext_vector_type(8)));
typedef float f32x4 __attribute__((ext_vector_type(4)));
union U16x8 { f16x8 v; f16 e[8]; };
union U16x4 { f16x4 v; f16 e[4]; };

// uni region (bytes):
//   phase 1-3: sWt f16[64][72] [0,9216) | sInW f32[16*64] [9216,13312)
//              sInb f32[64] [13312,13568) | sXr f32[90*17] [13568,19688)
//   phase 5-6: sPh f16[360][24] [0,17280)
//   phase 7:   sRa f32[2048] [0,8192) | sRb f32[2048] [8192,16384)
#define UNI_BYTES 19712
// big region: sx f16[96][72] [0,13824) -> overlaid by shF f32[96][72] [0,27648)
#define BIG_BYTES 27648

template <int LAYER>
__global__ __launch_bounds__(TPB, 6) void k_gat(
    const float* __restrict__ bp,
    const float* __restrict__ inW,
    const float* __restrict__ inb,
    const float* __restrict__ prevPre,
    const float* __restrict__ stPrev,
    const float* __restrict__ Wl,
    const float* __restrict__ asrc,
    const float* __restrict__ adst,
    float* __restrict__ outPre,
    float* __restrict__ partial,
    float* __restrict__ partialSq)
{
    __shared__ __align__(16) unsigned char uni[UNI_BYTES];
    __shared__ __align__(16) unsigned char big[BIG_BYTES];
    __shared__ float sAs[NH * HD], sAd[NH * HD];
    __shared__ float sSrc[NH][NN], sDst[NH][NN];
    __shared__ float sST[2 * CC];

    f16*   sWt  = (f16*)uni;
    float* sInW = (float*)(uni + 9216);
    float* sInb = (float*)(uni + 13312);
    float* sXr  = (float*)(uni + 13568);
    f16*   sPh  = (f16*)uni;
    float* sRa  = (float*)uni;
    float* sRb  = (float*)(uni + 8192);
    f16*   sx   = (f16*)big;        // [96][72] f16 (phases 1-3)
    float* shF  = (float*)big;      // [96][72] f32 (phases 3-6, overlays sx)

    const int b = blockIdx.x, t = threadIdx.x;
    const int cq = t & 15, ng = t >> 4;
    const int c4 = cq << 2;
    const int jcnt = (ng < NN - 64) ? 3 : 2;

    // ---------------- phase 1: stage weights / inputs
    for (int i = t; i < CC * CC; i += TPB) {
        int k = i >> 6, c = i & 63;
        sWt[c * SWP + k] = (f16)Wl[i];
    }
    if (t < NH * HD) { sAs[t] = asrc[t]; sAd[t] = adst[t]; }

    // zero pad rows 90..95 of sx (MFMA M-padding)
    if (t < (NP - NN) * (SHP / 4)) {
        int r = t / (SHP / 4), q = t % (SHP / 4);
        f16x4 z = {(f16)0, (f16)0, (f16)0, (f16)0};
        *(f16x4*)&sx[(NN + r) * SHP + q * 4] = z;
    }

    if (LAYER == 0) {
        for (int i = t; i < 16 * CC; i += TPB) sInW[i] = inW[i];
        if (t < CC) sInb[t] = inb[t];
        const float* bpb = bp + (size_t)b * (14 * NN);
        for (int i = t; i < 14 * NN; i += TPB) {
            int p = i / NN, n = i - p * NN;
            sXr[n * 17 + p] = bpb[i];
        }
        if (t < NN) {
            int y = t / 9, x = t - y * 9;
            sXr[t * 17 + 14] = (float)x / 9.0f;
            sXr[t * 17 + 15] = (float)y / 10.0f;
        }
    } else {
        if (t < 2 * CC) sST[t] = stPrev[t];
    }
    __syncthreads();

    // ---------------- phase 2: x -> sx (f16)
    if (LAYER == 0) {
        const int n0 = ng, n1 = ng + 32, n2 = (jcnt == 3) ? ng + 64 : ng;
        float acc[3][4] = {};
        #pragma unroll
        for (int k = 0; k < 16; k++) {
            float4 w = *(const float4*)&sInW[k * CC + c4];
            float x0 = sXr[n0 * 17 + k], x1 = sXr[n1 * 17 + k], x2 = sXr[n2 * 17 + k];
            acc[0][0] = fmaf(x0, w.x, acc[0][0]); acc[0][1] = fmaf(x0, w.y, acc[0][1]);
            acc[0][2] = fmaf(x0, w.z, acc[0][2]); acc[0][3] = fmaf(x0, w.w, acc[0][3]);
            acc[1][0] = fmaf(x1, w.x, acc[1][0]); acc[1][1] = fmaf(x1, w.y, acc[1][1]);
            acc[1][2] = fmaf(x1, w.z, acc[1][2]); acc[1][3] = fmaf(x1, w.w, acc[1][3]);
            acc[2][0] = fmaf(x2, w.x, acc[2][0]); acc[2][1] = fmaf(x2, w.y, acc[2][1]);
            acc[2][2] = fmaf(x2, w.z, acc[2][2]); acc[2][3] = fmaf(x2, w.w, acc[2][3]);
        }
        for (int j = 0; j < jcnt; j++) {
            int n = ng + 32 * j;
            f16x4 o;
            o.x = (f16)(acc[j][0] + sInb[c4 + 0]);
            o.y = (f16)(acc[j][1] + sInb[c4 + 1]);
            o.z = (f16)(acc[j][2] + sInb[c4 + 2]);
            o.w = (f16)(acc[j][3] + sInb[c4 + 3]);
            *(f16x4*)&sx[n * SHP + c4] = o;
        }
    } else {
        const float4* pv4 = (const float4*)(prevPre + (size_t)b * (NN * CC));
        for (int i4 = t; i4 < NN * CC / 4; i4 += TPB) {
            float4 v = pv4[i4];
            int n = i4 >> 4, c = (i4 & 15) << 2;
            float a0 = fmaf(v.x, sST[c + 0], sST[CC + c + 0]);
            float a1 = fmaf(v.y, sST[c + 1], sST[CC + c + 1]);
            float a2 = fmaf(v.z, sST[c + 2], sST[CC + c + 2]);
            float a3 = fmaf(v.w, sST[c + 3], sST[CC + c + 3]);
            f16x4 o;
            o.x = (f16)(a0 > 0.0f ? a0 : 0.0f);
            o.y = (f16)(a1 > 0.0f ? a1 : 0.0f);
            o.z = (f16)(a2 > 0.0f ? a2 : 0.0f);
            o.w = (f16)(a3 > 0.0f ? a3 : 0.0f);
            *(f16x4*)&sx[n * SHP + c] = o;
        }
    }
    __syncthreads();

    // ---------------- phase 3: h = x @ W via MFMA, C written as f32 to shF
    {
        const int w = t >> 6, lane = t & 63;
        const int lr = lane & 15, lg = lane >> 4;
        const int nt = w & 3, m0 = w >> 2;
        const f16x8 bf0 = *(const f16x8*)&sWt[(nt * 16 + lr) * SWP + lg * 8];
        const f16x8 bf1 = *(const f16x8*)&sWt[(nt * 16 + lr) * SWP + 32 + lg * 8];
        f16x8 af0[3], af1[3];
        #pragma unroll
        for (int mi = 0; mi < 3; mi++) {
            const int mt = m0 + 2 * mi;
            af0[mi] = *(const f16x8*)&sx[(mt * 16 + lr) * SHP + lg * 8];
            af1[mi] = *(const f16x8*)&sx[(mt * 16 + lr) * SHP + 32 + lg * 8];
        }
        __syncthreads();   // all sx reads done; shF writes may begin
        #pragma unroll
        for (int mi = 0; mi < 3; mi++) {
            const int mt = m0 + 2 * mi;
            f32x4 acc = {0.0f, 0.0f, 0.0f, 0.0f};
            acc = __builtin_amdgcn_mfma_f32_16x16x32_f16(af0[mi], bf0, acc, 0, 0, 0);
            acc = __builtin_amdgcn_mfma_f32_16x16x32_f16(af1[mi], bf1, acc, 0, 0, 0);
            const int row = mt * 16 + lg * 4, col = nt * 16 + lr;
            shF[(row + 0) * SHP + col] = acc[0];
            shF[(row + 1) * SHP + col] = acc[1];
            shF[(row + 2) * SHP + col] = acc[2];
            shF[(row + 3) * SHP + col] = acc[3];
        }
    }
    __syncthreads();

    // ---------------- phase 4: attention scores per (head, node), f32
    if (t < NH * NN) {
        int hh = t / NN, n = t - hh * NN;
        const float4* hv = (const float4*)&shF[n * SHP + hh * HD];
        float a = 0.0f, d = 0.0f;
        #pragma unroll
        for (int m = 0; m < 4; m++) {
            float4 h4 = hv[m];
            a = fmaf(h4.x, sAs[hh * HD + 4 * m + 0], a);
            a = fmaf(h4.y, sAs[hh * HD + 4 * m + 1], a);
            a = fmaf(h4.z, sAs[hh * HD + 4 * m + 2], a);
            a = fmaf(h4.w, sAs[hh * HD + 4 * m + 3], a);
            d = fmaf(h4.x, sAd[hh * HD + 4 * m + 0], d);
            d = fmaf(h4.y, sAd[hh * HD + 4 * m + 1], d);
            d = fmaf(h4.z, sAd[hh * HD + 4 * m + 2], d);
            d = fmaf(h4.w, sAd[hh * HD + 4 * m + 3], d);
        }
        sSrc[hh][n] = a; sDst[hh][n] = d;
    }
    __syncthreads();

    // ---------------- phase 5: positional-slot softmax -> sPh
    // (normalized in REGISTERS, 5x b64 vector stores — the R8-proven delta)
    if (t < NH * NN) {
        int hh = t / NN, n = t - hh * NN;
        int y = n / 9, x = n - y * 9;
        float si = sSrc[hh][n];
        float e[NSLOT];
        #pragma unroll
        for (int xx = 0; xx < 9; xx++) {
            int dx = xx > x ? xx - x : x - xx;
            float ee = si + sDst[hh][y * 9 + xx];
            ee = ee > 0.0f ? ee : 0.2f * ee;
            e[xx] = (dx <= 4) ? ee : -1e30f;
        }
        #pragma unroll
        for (int yy = 0; yy < 10; yy++) {
            int dy = yy > y ? yy - y : y - yy;
            float ee = si + sDst[hh][yy * 9 + x];
            ee = ee > 0.0f ? ee : 0.2f * ee;
            e[9 + yy] = (dy >= 1 && dy <= 5) ? ee : -1e30f;
        }
        float m = e[0];
        #pragma unroll
        for (int k = 1; k < NSLOT; k++) m = fmaxf(m, e[k]);
        float p[NSLOT];
        float s = 0.0f;
        #pragma unroll
        for (int k = 0; k < NSLOT; k++) { p[k] = __expf(e[k] - m); s += p[k]; }
        float inv = 1.0f / s;
        f16* pr = &sPh[t * PPITCH];
        #pragma unroll
        for (int q = 0; q < 5; q++) {
            U16x4 o;
            #pragma unroll
            for (int j = 0; j < 4; j++) {
                int k = 4 * q + j;
                o.e[j] = (k < NSLOT) ? (f16)(p[k] * inv) : (f16)0;
            }
            *(f16x4*)&pr[4 * q] = o.v;
        }
    }
    __syncthreads();

    // ---------------- phase 6: out = attn @ h, fixed 19-slot loops, f32 h
    const int hh2 = cq >> 2;
    float lsum[4] = {}, lsq[4] = {};
    float* op = outPre + (size_t)b * (NN * CC);
    for (int j = 0; j < jcnt; j++) {
        int n = ng + 32 * j;
        int y = n / 9, x = n - y * 9;
        const f16* pr = &sPh[(hh2 * NN + n) * PPITCH];
        U16x4 P0, P1, P2, P3, P4;
        P0.v = *(const f16x4*)&pr[0];
        P1.v = *(const f16x4*)&pr[4];
        P2.v = *(const f16x4*)&pr[8];
        P3.v = *(const f16x4*)&pr[12];
        P4.v = *(const f16x4*)&pr[16];
        float a0 = 0.0f, a1 = 0.0f, a2 = 0.0f, a3 = 0.0f;
        #pragma unroll
        for (int xx = 0; xx < 9; xx++) {
            float p = (xx < 4) ? (float)P0.e[xx]
                    : (xx < 8) ? (float)P1.e[xx - 4] : (float)P2.e[0];
            float4 h4 = *(const float4*)&shF[(y * 9 + xx) * SHP + c4];
            a0 = fmaf(p, h4.x, a0); a1 = fmaf(p, h4.y, a1);
            a2 = fmaf(p, h4.z, a2); a3 = fmaf(p, h4.w, a3);
        }
        #pragma unroll
        for (int yy = 0; yy < 10; yy++) {
            int k = 9 + yy;
            float p = (k < 12) ? (float)P2.e[k - 8]
                    : (k < 16) ? (float)P3.e[k - 12] : (float)P4.e[k - 16];
            float4 h4 = *(const float4*)&shF[(yy * 9 + x) * SHP + c4];
            a0 = fmaf(p, h4.x, a0); a1 = fmaf(p, h4.y, a1);
            a2 = fmaf(p, h4.z, a2); a3 = fmaf(p, h4.w, a3);
        }
        float4 o; o.x = a0; o.y = a1; o.z = a2; o.w = a3;
        *(float4*)&op[n * CC + c4] = o;
        lsum[0] += a0; lsum[1] += a1; lsum[2] += a2; lsum[3] += a3;
        lsq[0] = fmaf(a0, a0, lsq[0]); lsq[1] = fmaf(a1, a1, lsq[1]);
        lsq[2] = fmaf(a2, a2, lsq[2]); lsq[3] = fmaf(a3, a3, lsq[3]);
    }
    __syncthreads();   // sPh dead beyond here

    // ---------------- phase 7: BN partial sums
    #pragma unroll
    for (int q = 0; q < 4; q++) {
        sRa[ng * CC + c4 + q] = lsum[q];
        sRb[ng * CC + c4 + q] = lsq[q];
    }
    __syncthreads();
    if (t < CC) {
        float s = 0.0f, q2 = 0.0f;
        #pragma unroll
        for (int g = 0; g < 32; g++) {
            s  += sRa[g * CC + t];
            q2 += sRb[g * CC + t];
        }
        partial[(size_t)b * CC + t] = s;
        partialSq[(size_t)b * CC + t] = q2;
    }
}

// ------------------------------------------------------------- BN statistics
__global__ __launch_bounds__(256) void k_stats(
    const float* __restrict__ partial, const float* __restrict__ partialSq,
    const float* __restrict__ gamma, const float* __restrict__ beta,
    float* __restrict__ st)
{
    const int c = blockIdx.x, t = threadIdx.x;
    float s = 0.0f, q = 0.0f;
    for (int b = t; b < BB; b += 256) {
        s += partial[(size_t)b * CC + c];
        q += partialSq[(size_t)b * CC + c];
    }
    __shared__ float rs[256], rq[256];
    rs[t] = s; rq[t] = q;
    __syncthreads();
    for (int o = 128; o > 0; o >>= 1) {
        if (t < o) { rs[t] += rs[t + o]; rq[t] += rq[t + o]; }
        __syncthreads();
    }
    if (t == 0) {
        const float cntInv = 1.0f / (float)(BB * NN);
        float mean = rs[0] * cntInv;
        float var  = rq[0] * cntInv - mean * mean;
        float sc = gamma[c] * rsqrtf(var + 1e-5f);
        st[c] = sc;
        st[CC + c] = beta[c] - mean * sc;
    }
}

// ------------------------------------------------------------------- final
__global__ __launch_bounds__(256) void k_final(
    const float* __restrict__ pre, const float* __restrict__ st,
    const float* __restrict__ outW, const float* __restrict__ outb,
    float* __restrict__ out)
{
    __shared__ float sM[CC];
    __shared__ float sPart[4][CC];
    const int b = blockIdx.x, t = threadIdx.x;
    const int c = t & 63, p = t >> 6;
    const float* pv = pre + (size_t)b * (NN * CC);
    float s = st[c], sft = st[CC + c];
    float a = 0.0f;
    int nBeg = p * 23, nEnd = nBeg + 23 < NN ? nBeg + 23 : NN;
    for (int n = nBeg; n < nEnd; n++) {
        float v = fmaf(pv[n * CC + c], s, sft);
        a += (v > 0.0f ? v : 0.0f);
    }
    sPart[p][c] = a;
    __syncthreads();
    if (t < CC)
        sM[t] = (sPart[0][t] + sPart[1][t] + sPart[2][t] + sPart[3][t]) * (1.0f / (float)NN);
    __syncthreads();
    if (t < DOUT) {
        float acc = outb[t];
        #pragma unroll
        for (int cc2 = 0; cc2 < CC; cc2++) acc = fmaf(sM[cc2], outW[cc2 * DOUT + t], acc);
        out[(size_t)b * DOUT + t] = acc;
    }
}

// ------------------------------------------------------------------ launch
extern "C" void kernel_launch(void* const* d_in, const int* in_sizes, int n_in,
                              void* d_out, int out_size, void* d_ws, size_t ws_size,
                              hipStream_t stream) {
    (void)in_sizes; (void)n_in; (void)out_size; (void)ws_size;

    const float* bp   = (const float*)d_in[0];
    const float* inW  = (const float*)d_in[1];
    const float* inb  = (const float*)d_in[2];
    const float* W0   = (const float*)d_in[3];
    const float* as0  = (const float*)d_in[4];
    const float* ad0  = (const float*)d_in[5];
    const float* g0   = (const float*)d_in[6];
    const float* b0   = (const float*)d_in[7];
    const float* W1   = (const float*)d_in[8];
    const float* as1  = (const float*)d_in[9];
    const float* ad1  = (const float*)d_in[10];
    const float* g1   = (const float*)d_in[11];
    const float* b1   = (const float*)d_in[12];
    const float* outW = (const float*)d_in[13];
    const float* outb = (const float*)d_in[14];
    float* out = (float*)d_out;

    float* ws = (float*)d_ws;
    float* outPre    = ws;
    float* partial   = outPre + (size_t)BB * NN * CC;
    float* partialSq = partial + (size_t)BB * CC;
    float* st0       = partialSq + (size_t)BB * CC;
    float* st1       = st0 + 2 * CC;

    k_gat<0><<<BB, TPB, 0, stream>>>(bp, inW, inb, nullptr, nullptr,
                                     W0, as0, ad0, outPre, partial, partialSq);
    k_stats<<<CC, 256, 0, stream>>>(partial, partialSq, g0, b0, st0);
    k_gat<1><<<BB, TPB, 0, stream>>>(nullptr, nullptr, nullptr, outPre, st0,
                                     W1, as1, ad1, outPre, partial, partialSq);
    k_stats<<<CC, 256, 0, stream>>>(partial, partialSq, g1, b1, st1);
    k_final<<<BB, 256, 0, stream>>>(outPre, st1, outW, outb, out);
}